// Round 13
// baseline (1017.288 us; speedup 1.0000x reference)
//
#include <hip/hip_runtime.h>
#include <hip/hip_bf16.h>
#include <stdint.h>

typedef __bf16 bf16_t;
typedef __attribute__((ext_vector_type(8))) __bf16 bf16x8;
typedef __attribute__((ext_vector_type(4))) __bf16 bf16x4;
typedef __attribute__((ext_vector_type(4))) float f32x4;

#define O_N 100000
#define T_N 200000
#define LDN 136   // epilogue restage stride: 272B = 17x16B (aligned)
#define SCB 98    // scan blocks: ceil(O_N/1024)
#define POBJ 8    // poolS objects per wave (12500 waves > 8192 capacity -> churn TLP)

__device__ __forceinline__ bf16x8 cvt8(const float* p) {
    f32x4 a = *(const f32x4*)p;
    f32x4 b = *(const f32x4*)(p + 4);
    bf16x8 v;
    v[0] = (bf16_t)a[0]; v[1] = (bf16_t)a[1]; v[2] = (bf16_t)a[2]; v[3] = (bf16_t)a[3];
    v[4] = (bf16_t)b[0]; v[5] = (bf16_t)b[1]; v[6] = (bf16_t)b[2]; v[7] = (bf16_t)b[3];
    return v;
}

// async global->LDS, 16B per lane. LDS dest = wave-uniform base + lane*16 (m104);
// global source is per-lane (m173) so gathers / pre-swizzled sources are fine.
__device__ __forceinline__ void gload16(const bf16_t* g, bf16_t* l) {
    auto gp = reinterpret_cast<const __attribute__((address_space(1))) void*>(
        reinterpret_cast<uintptr_t>(g));
    auto lp = reinterpret_cast<__attribute__((address_space(3))) void*>(
        reinterpret_cast<uintptr_t>(l));
    __builtin_amdgcn_global_load_lds(gp, lp, 16, 0, 0);
}

// Bijective chunked XCD swizzle (m204). R2: FETCH 465->63MB on gemm2.
__device__ __forceinline__ void swz_block(int& mbase, int& nbase) {
    const int gx   = gridDim.x;
    const int nwg  = gx * gridDim.y;
    const int orig = blockIdx.y * gx + blockIdx.x;
    const int q = nwg >> 3, r = nwg & 7;
    const int xcd = orig & 7, lo = orig >> 3;
    const int base = (xcd < r) ? xcd * (q + 1) : r * (q + 1) + (xcd - r) * q;
    const int id = base + lo;
    nbase = (id % gx) * 128;
    mbase = (id / gx) * 128;
}

// ===== R4 core (verified R7: gemm2 178us, MfmaUtil 28.5) =====
// A,B tiles in LDS [128 rows][8 col8-groups]: elem (row,col8) at
// row*64 + (col8^(row&7))*8 (XOR swizzle). Both tiles double-buffered (64 KB).
// R5/R6: B-direct regresses; B stays in the coalesced DMA path.
// K-loop: stage(kt+1) BEFORE compute(kt); one vmcnt(0)+lgkmcnt(0) drain + one raw
// barrier per K-step.
//
// R9: ALL modes use operand-SWAPPED MFMA (acc = C^T) + coalesced transposed-D
// epilogue (normal-D's 64 scalar stores made gemm3 1.75x slower per block).
//
// R12: chunk size NCH=4 so per-chunk working set (hbuf 51.2 + writes 115.2 =
// 166 MB) fits the 256 MB L3 -> gemm5's hbuf read stays L3-resident
// (NCH=2's 333 MB evicted it; R10/R11 +50us regression, R12 recovered).
//
// MODE 1: A = gather-concat(objB[s]|predF|objB[o]) -> restage -> h[edge][512]
// MODE 2: A = h -> restage -> newT[edge][1024]; nb 4 -> newp (direct f32x4)
// MODE 5: like 2 but rows scatter to poolSrc[slot][512] (slot ids via `edges`=sslot2)
// MODE 3: A = pooledB; v *= 1/max(counts[m],1) in restage -> t3[obj][512]
// MODE 4: A = t3 -> direct transposed f32x4 -> new_obj[obj][128] (f32)
template<int MODE, int N, int K>
__launch_bounds__(256)
__global__ void gemm_k(const bf16_t* __restrict__ A,
                       const bf16_t* __restrict__ AobjB,   // MODE1: obj bf16 gather src
                       const float*  __restrict__ ApredF,  // MODE1: pred f32
                       const int*    __restrict__ edges,   // MODE1: edges; MODE5: sslot2
                       const float*  __restrict__ countsIn,
                       const bf16_t* __restrict__ Bt,      // N x K row-major bf16
                       const float*  __restrict__ bias,    // length N, f32
                       bf16_t*       __restrict__ CoutB,
                       float*        __restrict__ CoutF,
                       int M)
{
    // dbuf p in {0,1}: A @ p*16384, B @ p*16384+8192 (elems).
    // epilogue restage reuses smem as 128 x LDN (17408 elems <= 32768).
    __shared__ bf16_t smem[32768];
    __shared__ int sIdxL[128], oIdxL[128];

    const int tid  = threadIdx.x;
    const int lane = tid & 63;
    const int wv   = tid >> 6;
    const int wr   = (wv >> 1) * 64;   // wave row base in 128-tile (m)
    const int wc   = (wv & 1) * 64;    // wave col base (n)
    const int fr   = lane & 15;
    const int rowb = tid >> 3;         // staging row within 32-row t-block
    const int colS = ((tid & 7) ^ (rowb & 7)) << 3;   // inverse-swizzled src col (elems)
    int mbase, nbase;
    swz_block(mbase, nbase);

    if constexpr (MODE == 1 || MODE == 5) {
        if (tid < 128) {
            int g = mbase + tid; if (g > M - 1) g = M - 1;
            sIdxL[tid] = edges[2 * g];
            oIdxL[tid] = edges[2 * g + 1];
        }
    }
    __syncthreads();

    f32x4 acc[4][4];
    #pragma unroll
    for (int i = 0; i < 4; i++)
        #pragma unroll
        for (int j = 0; j < 4; j++)
            acc[i][j] = (f32x4){0.f, 0.f, 0.f, 0.f};

    auto stage = [&](int p, int k0) {
        bf16_t* lA = smem + p * 16384;
        bf16_t* lB = lA + 8192;
        if constexpr (MODE == 1) {
            if (k0 < 128 || k0 >= 256) {           // obj segments: bf16 gather DMA
                const bool sSeg = (k0 < 128);
                const int  seg0 = sSeg ? k0 : (k0 - 256);
                #pragma unroll
                for (int t = 0; t < 4; ++t) {
                    int row = t * 32 + rowb;
                    int gr  = sSeg ? sIdxL[row] : oIdxL[row];
                    gload16(AobjB + (size_t)gr * 128 + seg0 + colS,
                            &lA[t * 2048 + wv * 512]);
                }
            } else {                               // pred segment: f32->bf16 reg-stage
                #pragma unroll
                for (int t = 0; t < 4; ++t) {
                    int row  = t * 32 + rowb;
                    int grow = mbase + row; if (grow > M - 1) grow = M - 1;
                    bf16x8 v = cvt8(ApredF + (size_t)grow * 128 + (k0 - 128)
                                    + ((tid & 7) << 3));
                    *(bf16x8*)&lA[t * 2048 + rowb * 64 + colS] = v;  // swizzled write
                }
            }
        } else {
            #pragma unroll
            for (int t = 0; t < 4; ++t) {
                int row  = t * 32 + rowb;
                int grow = mbase + row; if (grow > M - 1) grow = M - 1;
                gload16(A + (size_t)grow * K + k0 + colS, &lA[t * 2048 + wv * 512]);
            }
        }
        #pragma unroll
        for (int t = 0; t < 4; ++t) {
            int row = t * 32 + rowb;
            gload16(Bt + (size_t)(nbase + row) * K + k0 + colS,
                    &lB[t * 2048 + wv * 512]);
        }
    };

    const int KT = K / 64;
    stage(0, 0);
    asm volatile("s_waitcnt vmcnt(0) lgkmcnt(0)" ::: "memory");
    __builtin_amdgcn_s_barrier();

    int cur = 0;
    for (int kt = 0; kt < KT; ++kt) {
        if (kt + 1 < KT) stage(cur ^ 1, (kt + 1) * 64);   // prefetch overlaps MFMA
        const bf16_t* lA = smem + cur * 16384;
        const bf16_t* lB = lA + 8192;
        #pragma unroll
        for (int ks8 = 0; ks8 < 8; ks8 += 4) {
            const int c8 = (ks8 + (lane >> 4)) ^ (lane & 7);   // swizzled read col8
            bf16x8 af[4], bfv[4];
            #pragma unroll
            for (int i = 0; i < 4; i++)
                af[i] = *(const bf16x8*)&lA[(wr + i * 16 + fr) * 64 + (c8 << 3)];
            #pragma unroll
            for (int j = 0; j < 4; j++)
                bfv[j] = *(const bf16x8*)&lB[(wc + j * 16 + fr) * 64 + (c8 << 3)];
            #pragma unroll
            for (int i = 0; i < 4; i++)
                #pragma unroll
                for (int j = 0; j < 4; j++)
                    // swapped operands (ALL modes): acc = C^T
                    acc[i][j] = __builtin_amdgcn_mfma_f32_16x16x32_bf16(
                        bfv[j], af[i], acc[i][j], 0, 0, 0);
        }
        asm volatile("s_waitcnt vmcnt(0) lgkmcnt(0)" ::: "memory");
        __builtin_amdgcn_s_barrier();
        cur ^= 1;
    }

    // ===== transposed-D epilogues: col(lane&15)=m (row), reg r = n-col offset =====
    if constexpr (MODE == 4) {
        #pragma unroll
        for (int j = 0; j < 4; j++) {
            int nl = wc + j * 16 + (lane >> 4) * 4;
            f32x4 bv = *(const f32x4*)&bias[nbase + nl];
            #pragma unroll
            for (int i = 0; i < 4; i++) {
                int grow = mbase + wr + i * 16 + fr;
                if (grow >= M) continue;
                float v0 = acc[i][j][0] + bv[0]; v0 = v0 > 0.f ? v0 : 0.f;
                float v1 = acc[i][j][1] + bv[1]; v1 = v1 > 0.f ? v1 : 0.f;
                float v2 = acc[i][j][2] + bv[2]; v2 = v2 > 0.f ? v2 : 0.f;
                float v3 = acc[i][j][3] + bv[3]; v3 = v3 > 0.f ? v3 : 0.f;
                f32x4 o = {v0, v1, v2, v3};
                *(f32x4*)&CoutF[(size_t)grow * 128 + nbase + nl] = o;
            }
        }
    } else {
        const bool isNewp = (MODE == 2 || MODE == 5) && (nbase == 512);
        if (isNewp) {
            // newp block: direct f32 stores (precision: newp stays f32)
            #pragma unroll
            for (int j = 0; j < 4; j++) {
                int nl = wc + j * 16 + (lane >> 4) * 4;
                f32x4 bv = *(const f32x4*)&bias[nbase + nl];
                #pragma unroll
                for (int i = 0; i < 4; i++) {
                    int grow = mbase + wr + i * 16 + fr;
                    if (grow >= M) continue;
                    float v0 = acc[i][j][0] + bv[0]; v0 = v0 > 0.f ? v0 : 0.f;
                    float v1 = acc[i][j][1] + bv[1]; v1 = v1 > 0.f ? v1 : 0.f;
                    float v2 = acc[i][j][2] + bv[2]; v2 = v2 > 0.f ? v2 : 0.f;
                    float v3 = acc[i][j][3] + bv[3]; v3 = v3 > 0.f ? v3 : 0.f;
                    f32x4 o = {v0, v1, v2, v3};
                    *(f32x4*)&CoutF[(size_t)grow * 128 + nl] = o;   // nbase+nl-512==nl
                }
            }
        } else {
            // per-m-row reciprocal counts (MODE 3 only): m-row = wr + i*16 + fr
            float rcv[4];
            if constexpr (MODE == 3) {
                #pragma unroll
                for (int i = 0; i < 4; i++) {
                    int grow = mbase + wr + i * 16 + fr;
                    if (grow > M - 1) grow = M - 1;
                    float c = countsIn[grow]; c = c > 1.f ? c : 1.f;
                    rcv[i] = 1.f / c;
                }
            }
            // restage C^T-tile into LDS (m-major), then coalesced row stores
            #pragma unroll
            for (int j = 0; j < 4; j++) {
                int nl = wc + j * 16 + (lane >> 4) * 4;
                f32x4 bv = *(const f32x4*)&bias[nbase + nl];
                #pragma unroll
                for (int i = 0; i < 4; i++) {
                    int ml = wr + i * 16 + fr;
                    float s = (MODE == 3) ? rcv[i] : 1.f;
                    float v0 = acc[i][j][0] * s + bv[0]; v0 = v0 > 0.f ? v0 : 0.f;
                    float v1 = acc[i][j][1] * s + bv[1]; v1 = v1 > 0.f ? v1 : 0.f;
                    float v2 = acc[i][j][2] * s + bv[2]; v2 = v2 > 0.f ? v2 : 0.f;
                    float v3 = acc[i][j][3] * s + bv[3]; v3 = v3 > 0.f ? v3 : 0.f;
                    bf16x4 pv;
                    pv[0] = (bf16_t)v0; pv[1] = (bf16_t)v1;
                    pv[2] = (bf16_t)v2; pv[3] = (bf16_t)v3;
                    *(bf16x4*)&smem[ml * LDN + nl] = pv;
                }
            }
            __syncthreads();
            const bool isS = (nbase < 512);      // MODE 2/5 s-vs-o half
            #pragma unroll
            for (int rr = 0; rr < 8; ++rr) {
                int row  = rr * 16 + (tid >> 4);
                int grow = mbase + row;
                if (grow >= M) continue;
                bf16x8 v = *(const bf16x8*)&smem[row * LDN + (tid & 15) * 8];
                if constexpr (MODE == 1 || MODE == 3) {
                    *(bf16x8*)&CoutB[(size_t)grow * 512 + nbase + (tid & 15) * 8] = v;
                } else if constexpr (MODE == 2) {
                    int cb = isS ? nbase : (nbase - 128);
                    *(bf16x8*)&CoutB[(size_t)grow * 1024 + cb + (tid & 15) * 8] = v;
                } else {   // MODE 5: scatter to poolSrc[slot][512]
                    int cb2  = isS ? nbase : (nbase - 640);
                    int drow = isS ? sIdxL[row] : oIdxL[row];
                    *(bf16x8*)&CoutB[(size_t)drow * 512 + cb2 + (tid & 15) * 8] = v;
                }
            }
        }
    }
}

// fused prologue: obj f32->bf16 (1.6M x8), 4 weight transposes (1,114,112), counts
__global__ void prep_k(const float* __restrict__ obj, bf16_t* __restrict__ objB,
                       const float* __restrict__ W1, bf16_t* __restrict__ W1t,
                       const float* __restrict__ W2, bf16_t* __restrict__ W2t,
                       const float* __restrict__ W3, bf16_t* __restrict__ W3t,
                       const float* __restrict__ W4, bf16_t* __restrict__ W4t,
                       const int* __restrict__ edges, float* __restrict__ counts) {
    int idx = blockIdx.x * 256 + threadIdx.x;
    if (idx < 1600000) {
        bf16x8 v = cvt8(obj + (size_t)idx * 8);
        *(bf16x8*)(objB + (size_t)idx * 8) = v;
        return;
    }
    idx -= 1600000;
    if (idx < 1114112) {
        const float* in; bf16_t* out; int K, N;
        if (idx < 196608)       { in = W1; out = W1t; K = 384; N = 512;  }
        else if (idx < 786432)  { in = W2; out = W2t; K = 512; N = 1152; idx -= 196608; }
        else if (idx < 1048576) { in = W3; out = W3t; K = 512; N = 512;  idx -= 786432; }
        else                    { in = W4; out = W4t; K = 512; N = 128;  idx -= 1048576; }
        int k = idx / N, n = idx - k * N;
        out[n * K + k] = (bf16_t)in[idx];
        return;
    }
    idx -= 1114112;
    if (idx < T_N) {
        unsafeAtomicAdd(&counts[edges[2 * idx]],     1.f);
        unsafeAtomicAdd(&counts[edges[2 * idx + 1]], 1.f);
    }
}

// per-block sums of (int)counts
__launch_bounds__(1024)
__global__ void scan1_k(const float* __restrict__ counts, int* __restrict__ bsum) {
    __shared__ int wsum[16];
    const int tid = threadIdx.x, lane = tid & 63, wv = tid >> 6;
    int i = blockIdx.x * 1024 + tid;
    int v = (i < O_N) ? (int)counts[i] : 0;
    #pragma unroll
    for (int d = 1; d < 64; d <<= 1) v += __shfl_xor(v, d, 64);
    if (lane == 0) wsum[wv] = v;
    __syncthreads();
    if (tid == 0) {
        int s = 0;
        #pragma unroll
        for (int k = 0; k < 16; ++k) s += wsum[k];
        bsum[blockIdx.x] = s;
    }
}

// fused scan2+scan3: each block computes its own bsum prefix, then local scan.
__launch_bounds__(1024)
__global__ void scan23_k(const float* __restrict__ counts, const int* __restrict__ bsum,
                         int* __restrict__ offsets, int* __restrict__ cursor) {
    __shared__ int wsum[16];
    __shared__ int pre2[2];
    const int tid = threadIdx.x, lane = tid & 63, wv = tid >> 6;
    int i = blockIdx.x * 1024 + tid;
    int x = (i < O_N) ? (int)counts[i] : 0;
    int v = x;
    #pragma unroll
    for (int d = 1; d < 64; d <<= 1) {
        int u = __shfl_up(v, d, 64);
        if (lane >= d) v += u;
    }
    if (lane == 63) wsum[wv] = v;
    if (tid < 128) {                       // prefix of bsum[0..blockIdx.x)
        int b = (tid < blockIdx.x) ? bsum[tid] : 0;   // blockIdx.x <= 97 < 128
        #pragma unroll
        for (int d = 1; d < 64; d <<= 1) b += __shfl_xor(b, d, 64);
        if (lane == 0) pre2[tid >> 6] = b;
    }
    __syncthreads();
    if (tid == 0) {
        int run = pre2[0] + pre2[1];
        #pragma unroll
        for (int k = 0; k < 16; ++k) { int t2 = wsum[k]; wsum[k] = run; run += t2; }
        if (blockIdx.x == SCB - 1) offsets[O_N] = run;
    }
    __syncthreads();
    if (i < O_N) { int e = wsum[wv] + (v - x); offsets[i] = e; cursor[i] = e; }
}

// slot assignment: slots[p]=(t<<1)|half (legacy pool) AND sslot2[2t]={p,q} (scatter)
__global__ void fill_k(const int* __restrict__ edges, int* __restrict__ cursor,
                       int* __restrict__ slots, int* __restrict__ sslot2) {
    int t = blockIdx.x * 256 + threadIdx.x;
    if (t < T_N) {
        int s = edges[2 * t], o = edges[2 * t + 1];
        int p = atomicAdd(&cursor[s], 1);
        slots[p] = t << 1;
        int q = atomicAdd(&cursor[o], 1);
        slots[q] = (t << 1) | 1;
        sslot2[2 * t]     = p;
        sslot2[2 * t + 1] = q;
    }
}

// scatter-mode pool (R13): POBJ objects per wave, ONE coalesced offsets preload
// (lanes 0..POBJ) + shfl broadcast -> amortizes the dependent offset-load chain
// 8x vs R9/R12's one-object-per-wave (which paid ~600cy offset latency per
// ~500cy of data). 12500 waves keeps churn TLP (R10's 8192-wave variant lost it).
__launch_bounds__(256)
__global__ void poolS_k(const bf16_t* __restrict__ poolSrc,
                        const int* __restrict__ offsets,
                        bf16_t* __restrict__ pooledB) {
    const int wvid = (blockIdx.x * 256 + threadIdx.x) >> 6;
    const int lane = threadIdx.x & 63;
    const int g0 = wvid * POBJ;
    if (g0 >= O_N) return;
    int nobj = O_N - g0; if (nobj > POBJ) nobj = POBJ;
    int offl = (lane <= nobj) ? offsets[g0 + lane] : 0;   // one coalesced load
    for (int k = 0; k < nobj; ++k) {
        const int s0 = __shfl(offl, k, 64);
        const int s1 = __shfl(offl, k + 1, 64);
        float acc[8];
        #pragma unroll
        for (int l = 0; l < 8; l++) acc[l] = 0.f;
        int j = s0;
        for (; j + 3 < s1; j += 4) {       // 4-deep: all four loads in flight
            bf16x8 a = *(const bf16x8*)(poolSrc + (size_t)j * 512 + lane * 8);
            bf16x8 b = *(const bf16x8*)(poolSrc + (size_t)(j + 1) * 512 + lane * 8);
            bf16x8 c = *(const bf16x8*)(poolSrc + (size_t)(j + 2) * 512 + lane * 8);
            bf16x8 d = *(const bf16x8*)(poolSrc + (size_t)(j + 3) * 512 + lane * 8);
            #pragma unroll
            for (int l = 0; l < 8; l++)
                acc[l] += ((float)a[l] + (float)b[l]) + ((float)c[l] + (float)d[l]);
        }
        for (; j < s1; ++j) {
            bf16x8 a = *(const bf16x8*)(poolSrc + (size_t)j * 512 + lane * 8);
            #pragma unroll
            for (int l = 0; l < 8; l++) acc[l] += (float)a[l];
        }
        bf16x8 o;
        #pragma unroll
        for (int l = 0; l < 8; l++) o[l] = (bf16_t)acc[l];
        *(bf16x8*)(pooledB + (size_t)(g0 + k) * 512 + lane * 8) = o;
    }
}

// legacy pool (fallback): wave-cooperative slot preload + shfl broadcast.
template<bool FIRST>
__launch_bounds__(256)
__global__ void pool_k(const bf16_t* __restrict__ newT, const int* __restrict__ offsets,
                       const int* __restrict__ slots, bf16_t* __restrict__ pooledB,
                       int tbase, int tcount) {
    const int gw   = (blockIdx.x * 256 + threadIdx.x) >> 6;
    const int lane = threadIdx.x & 63;
    if (gw >= O_N) return;
    const int s0 = offsets[gw], s1 = offsets[gw + 1];
    float acc[8];
    #pragma unroll
    for (int l = 0; l < 8; l++) acc[l] = 0.f;
    for (int base = s0; base < s1; base += 64) {
        int nn = s1 - base; if (nn > 64) nn = 64;
        int myslot = (lane < nn) ? slots[base + lane] : 0;   // one coalesced load
        for (int j = 0; j < nn; ++j) {
            int sl = __shfl(myslot, j, 64);
            int lt = (sl >> 1) - tbase;
            if ((unsigned)lt >= (unsigned)tcount) continue;
            const bf16_t* p = newT + (size_t)lt * 1024 + (sl & 1) * 512 + lane * 8;
            bf16x8 v = *(const bf16x8*)p;
            #pragma unroll
            for (int l = 0; l < 8; l++) acc[l] += (float)v[l];
        }
    }
    bf16_t* dst = pooledB + (size_t)gw * 512 + lane * 8;
    if constexpr (!FIRST) {
        bf16x8 prev = *(const bf16x8*)dst;
        #pragma unroll
        for (int l = 0; l < 8; l++) acc[l] += (float)prev[l];
    }
    bf16x8 o;
    #pragma unroll
    for (int l = 0; l < 8; l++) o[l] = (bf16_t)acc[l];
    *(bf16x8*)dst = o;
}

extern "C" void kernel_launch(void* const* d_in, const int* in_sizes, int n_in,
                              void* d_out, int out_size, void* d_ws, size_t ws_size,
                              hipStream_t stream) {
    const float* obj  = (const float*)d_in[0];
    const float* pred = (const float*)d_in[1];
    const int*   edges= (const int*)d_in[2];
    const float* W1 = (const float*)d_in[3];
    const float* b1 = (const float*)d_in[4];
    const float* W2 = (const float*)d_in[5];
    const float* b2 = (const float*)d_in[6];
    const float* W3 = (const float*)d_in[7];
    const float* b3 = (const float*)d_in[8];
    const float* W4 = (const float*)d_in[9];
    const float* b4 = (const float*)d_in[10];
    float* out = (float*)d_out;   // [new_obj O_N*128 | new_p T_N*128], f32

    char* ws = (char*)d_ws;
    auto AL = [](size_t x) { return (x + 255) & ~(size_t)255; };

    // ---- small fixed region (both paths) ----
    size_t o_counts = 0;
    size_t o_offs   = AL(o_counts + (size_t)O_N * 4);
    size_t o_curs   = AL(o_offs   + (size_t)(O_N + 1) * 4);
    size_t o_bsum   = AL(o_curs   + (size_t)O_N * 4);
    size_t o_slots  = AL(o_bsum   + (size_t)128 * 4);
    size_t o_ss2    = AL(o_slots  + (size_t)2 * T_N * 4);     // slots 1.6 MB
    size_t o_objB   = AL(o_ss2    + (size_t)2 * T_N * 4);     // sslot2 1.6 MB
    size_t o_w1     = AL(o_objB   + (size_t)O_N * 128 * 2);   // objB 25.6 MB
    size_t o_w2     = AL(o_w1 + (size_t)384 * 512 * 2);
    size_t o_w3     = AL(o_w2 + (size_t)512 * 1152 * 2);
    size_t o_w4     = AL(o_w3 + (size_t)512 * 512 * 2);
    size_t o_end    = AL(o_w4 + (size_t)512 * 128 * 2);       // ~32.3 MB

    const size_t pbSz = (size_t)O_N * 512 * 2;                // pooledB 102.4 MB
    const size_t psSz = (size_t)2 * T_N * 512 * 2;            // poolSrc 409.6 MB
    const size_t t3sz = (size_t)O_N * 512 * 2;                // 102.4 MB

    // Tier A (scatter, NCH=4 — R12-verified): aliasing keeps cost ~544 MB:
    //   hbuf region sized max(R*1024, pbSz) = pbSz; reused as pooledB;
    //   poolSrc reused as t3 after poolS.
    bool scatter = false;
    const int NCH_SC = 4;
    {
        size_t hb = (size_t)(T_N / NCH_SC) * 1024; if (hb < pbSz) hb = pbSz;
        size_t need = o_end + AL(hb) + psSz;                  // t3sz <= psSz
        if (ws_size >= need) scatter = true;
    }
    int NCH = NCH_SC;
    if (!scatter) {   // fallback: pooledB must persist across chunks -> own region
        NCH = 8;
        for (int n : {2, 4}) {
            size_t R = (size_t)T_N / n;
            size_t chunk = AL(R * 1024) + R * 2048;
            size_t need  = o_end + AL(pbSz) + (chunk > t3sz ? chunk : t3sz);
            if (ws_size >= need) { NCH = n; break; }
        }
    }
    const int R  = T_N / NCH;
    const int MB = (R + 127) / 128;

    float*  counts  = (float*)(ws + o_counts);
    int*    offs    = (int*)(ws + o_offs);
    int*    curs    = (int*)(ws + o_curs);
    int*    bsum    = (int*)(ws + o_bsum);
    int*    slots   = (int*)(ws + o_slots);
    int*    sslot2  = (int*)(ws + o_ss2);
    bf16_t* objB    = (bf16_t*)(ws + o_objB);
    bf16_t* W1t     = (bf16_t*)(ws + o_w1);
    bf16_t* W2t     = (bf16_t*)(ws + o_w2);
    bf16_t* W3t     = (bf16_t*)(ws + o_w3);
    bf16_t* W4t     = (bf16_t*)(ws + o_w4);

    bf16_t *hbuf, *pooledB, *stage2, *t3;
    if (scatter) {
        size_t hb = (size_t)R * 1024; if (hb < pbSz) hb = pbSz;
        hbuf    = (bf16_t*)(ws + o_end);
        pooledB = hbuf;                          // aliases hbuf (dead before poolS)
        stage2  = (bf16_t*)(ws + o_end + AL(hb));   // poolSrc
        t3      = stage2;                        // aliases poolSrc (dead after poolS)
    } else {
        pooledB = (bf16_t*)(ws + o_end);
        hbuf    = (bf16_t*)(ws + o_end + AL(pbSz));
        stage2  = (bf16_t*)((char*)hbuf + AL((size_t)R * 1024));  // newT
        t3      = hbuf;                          // reuse after pooling done
    }

    hipMemsetAsync(counts, 0, (size_t)O_N * 4, stream);

    prep_k<<<(2914112 + 255) / 256, 256, 0, stream>>>(
        obj, objB, W1, W1t, W2, W2t, W3, W3t, W4, W4t, edges, counts);
    scan1_k<<<SCB, 1024, 0, stream>>>(counts, bsum);
    scan23_k<<<SCB, 1024, 0, stream>>>(counts, bsum, offs, curs);
    fill_k<<<(T_N + 255) / 256, 256, 0, stream>>>(edges, curs, slots, sslot2);

    for (int c = 0; c < NCH; ++c) {
        const int row0 = c * R;
        gemm_k<1, 512, 384><<<dim3(4, MB), 256, 0, stream>>>(
            nullptr, objB, pred + (size_t)row0 * 128, edges + 2 * row0,
            nullptr, W1t, b1, hbuf, nullptr, R);
        if (scatter) {
            gemm_k<5, 1152, 512><<<dim3(9, MB), 256, 0, stream>>>(
                hbuf, nullptr, nullptr, sslot2 + 2 * row0,
                nullptr, W2t, b2, stage2,
                out + (size_t)O_N * 128 + (size_t)row0 * 128, R);
        } else {
            gemm_k<2, 1152, 512><<<dim3(9, MB), 256, 0, stream>>>(
                hbuf, nullptr, nullptr, nullptr,
                nullptr, W2t, b2, stage2,
                out + (size_t)O_N * 128 + (size_t)row0 * 128, R);
            if (c == 0)
                pool_k<true><<<(O_N * 64 + 255) / 256, 256, 0, stream>>>(
                    stage2, offs, slots, pooledB, row0, R);
            else
                pool_k<false><<<(O_N * 64 + 255) / 256, 256, 0, stream>>>(
                    stage2, offs, slots, pooledB, row0, R);
        }
    }
    if (scatter) {
        const int NW = (O_N + POBJ - 1) / POBJ;            // 12500 waves
        poolS_k<<<(NW * 64 + 255) / 256, 256, 0, stream>>>(stage2, offs, pooledB);
    }

    // t3 = relu((pooledB @ W3) * 1/max(counts,1) + b3)   (div fused into restage)
    gemm_k<3, 512, 512><<<dim3(4, 782), 256, 0, stream>>>(
        pooledB, nullptr, nullptr, nullptr, counts,
        W3t, b3, t3, nullptr, O_N);
    // new_obj = relu(t3 @ W4 + b4)
    gemm_k<4, 128, 512><<<dim3(1, 782), 256, 0, stream>>>(
        t3, nullptr, nullptr, nullptr, nullptr,
        W4t, b4, nullptr, out, O_N);
}

// Round 14
// 980.942 us; speedup vs baseline: 1.0371x; 1.0371x over previous
//
#include <hip/hip_runtime.h>
#include <hip/hip_bf16.h>
#include <stdint.h>

typedef __bf16 bf16_t;
typedef __attribute__((ext_vector_type(8))) __bf16 bf16x8;
typedef __attribute__((ext_vector_type(4))) __bf16 bf16x4;
typedef __attribute__((ext_vector_type(4))) float f32x4;

#define O_N 100000
#define T_N 200000
#define LDN 136   // epilogue restage stride: 272B = 17x16B (aligned)
#define SCB 98    // scan blocks: ceil(O_N/1024)

__device__ __forceinline__ bf16x8 cvt8(const float* p) {
    f32x4 a = *(const f32x4*)p;
    f32x4 b = *(const f32x4*)(p + 4);
    bf16x8 v;
    v[0] = (bf16_t)a[0]; v[1] = (bf16_t)a[1]; v[2] = (bf16_t)a[2]; v[3] = (bf16_t)a[3];
    v[4] = (bf16_t)b[0]; v[5] = (bf16_t)b[1]; v[6] = (bf16_t)b[2]; v[7] = (bf16_t)b[3];
    return v;
}

// async global->LDS, 16B per lane. LDS dest = wave-uniform base + lane*16 (m104);
// global source is per-lane (m173) so gathers / pre-swizzled sources are fine.
__device__ __forceinline__ void gload16(const bf16_t* g, bf16_t* l) {
    auto gp = reinterpret_cast<const __attribute__((address_space(1))) void*>(
        reinterpret_cast<uintptr_t>(g));
    auto lp = reinterpret_cast<__attribute__((address_space(3))) void*>(
        reinterpret_cast<uintptr_t>(l));
    __builtin_amdgcn_global_load_lds(gp, lp, 16, 0, 0);
}

// Bijective chunked XCD swizzle (m204). R2: FETCH 465->63MB on gemm2.
__device__ __forceinline__ void swz_block(int& mbase, int& nbase) {
    const int gx   = gridDim.x;
    const int nwg  = gx * gridDim.y;
    const int orig = blockIdx.y * gx + blockIdx.x;
    const int q = nwg >> 3, r = nwg & 7;
    const int xcd = orig & 7, lo = orig >> 3;
    const int base = (xcd < r) ? xcd * (q + 1) : r * (q + 1) + (xcd - r) * q;
    const int id = base + lo;
    nbase = (id % gx) * 128;
    mbase = (id / gx) * 128;
}

// ===== R4 core (verified R7: gemm2 178us, MfmaUtil 28.5) =====
// A,B tiles in LDS [128 rows][8 col8-groups]: elem (row,col8) at
// row*64 + (col8^(row&7))*8 (XOR swizzle). Both tiles double-buffered (64 KB).
// R5/R6: B-direct regresses; B stays in the coalesced DMA path.
// K-loop: stage(kt+1) BEFORE compute(kt); one vmcnt(0)+lgkmcnt(0) drain + one raw
// barrier per K-step.
//
// R9: ALL modes use operand-SWAPPED MFMA (acc = C^T) + coalesced transposed-D
// epilogue (normal-D's 64 scalar stores made gemm3 1.75x slower per block).
//
// R12: chunk size NCH=4 so per-chunk working set (hbuf 51.2 + writes 115.2 =
// 166 MB) fits the 256 MB L3 -> gemm5's hbuf read stays L3-resident
// (NCH=2's 333 MB evicted it; R10/R11 +50us regression, R12 recovered).
//
// R13 lesson: poolS wave-grouping (8 obj/wave) serialized chains, 117->130us;
// one-object-per-wave + 4-deep pipelining is the verified best (R14 revert).
//
// MODE 1: A = gather-concat(objB[s]|predF|objB[o]) -> restage -> h[edge][512]
// MODE 2: A = h -> restage -> newT[edge][1024]; nb 4 -> newp (direct f32x4)
// MODE 5: like 2 but rows scatter to poolSrc[slot][512] (slot ids via `edges`=sslot2)
// MODE 3: A = pooledB; v *= 1/max(counts[m],1) in restage -> t3[obj][512]
// MODE 4: A = t3 -> direct transposed f32x4 -> new_obj[obj][128] (f32)
template<int MODE, int N, int K>
__launch_bounds__(256)
__global__ void gemm_k(const bf16_t* __restrict__ A,
                       const bf16_t* __restrict__ AobjB,   // MODE1: obj bf16 gather src
                       const float*  __restrict__ ApredF,  // MODE1: pred f32
                       const int*    __restrict__ edges,   // MODE1: edges; MODE5: sslot2
                       const float*  __restrict__ countsIn,
                       const bf16_t* __restrict__ Bt,      // N x K row-major bf16
                       const float*  __restrict__ bias,    // length N, f32
                       bf16_t*       __restrict__ CoutB,
                       float*        __restrict__ CoutF,
                       int M)
{
    // dbuf p in {0,1}: A @ p*16384, B @ p*16384+8192 (elems).
    // epilogue restage reuses smem as 128 x LDN (17408 elems <= 32768).
    __shared__ bf16_t smem[32768];
    __shared__ int sIdxL[128], oIdxL[128];

    const int tid  = threadIdx.x;
    const int lane = tid & 63;
    const int wv   = tid >> 6;
    const int wr   = (wv >> 1) * 64;   // wave row base in 128-tile (m)
    const int wc   = (wv & 1) * 64;    // wave col base (n)
    const int fr   = lane & 15;
    const int rowb = tid >> 3;         // staging row within 32-row t-block
    const int colS = ((tid & 7) ^ (rowb & 7)) << 3;   // inverse-swizzled src col (elems)
    int mbase, nbase;
    swz_block(mbase, nbase);

    if constexpr (MODE == 1 || MODE == 5) {
        if (tid < 128) {
            int g = mbase + tid; if (g > M - 1) g = M - 1;
            sIdxL[tid] = edges[2 * g];
            oIdxL[tid] = edges[2 * g + 1];
        }
    }
    __syncthreads();

    f32x4 acc[4][4];
    #pragma unroll
    for (int i = 0; i < 4; i++)
        #pragma unroll
        for (int j = 0; j < 4; j++)
            acc[i][j] = (f32x4){0.f, 0.f, 0.f, 0.f};

    auto stage = [&](int p, int k0) {
        bf16_t* lA = smem + p * 16384;
        bf16_t* lB = lA + 8192;
        if constexpr (MODE == 1) {
            if (k0 < 128 || k0 >= 256) {           // obj segments: bf16 gather DMA
                const bool sSeg = (k0 < 128);
                const int  seg0 = sSeg ? k0 : (k0 - 256);
                #pragma unroll
                for (int t = 0; t < 4; ++t) {
                    int row = t * 32 + rowb;
                    int gr  = sSeg ? sIdxL[row] : oIdxL[row];
                    gload16(AobjB + (size_t)gr * 128 + seg0 + colS,
                            &lA[t * 2048 + wv * 512]);
                }
            } else {                               // pred segment: f32->bf16 reg-stage
                #pragma unroll
                for (int t = 0; t < 4; ++t) {
                    int row  = t * 32 + rowb;
                    int grow = mbase + row; if (grow > M - 1) grow = M - 1;
                    bf16x8 v = cvt8(ApredF + (size_t)grow * 128 + (k0 - 128)
                                    + ((tid & 7) << 3));
                    *(bf16x8*)&lA[t * 2048 + rowb * 64 + colS] = v;  // swizzled write
                }
            }
        } else {
            #pragma unroll
            for (int t = 0; t < 4; ++t) {
                int row  = t * 32 + rowb;
                int grow = mbase + row; if (grow > M - 1) grow = M - 1;
                gload16(A + (size_t)grow * K + k0 + colS, &lA[t * 2048 + wv * 512]);
            }
        }
        #pragma unroll
        for (int t = 0; t < 4; ++t) {
            int row = t * 32 + rowb;
            gload16(Bt + (size_t)(nbase + row) * K + k0 + colS,
                    &lB[t * 2048 + wv * 512]);
        }
    };

    const int KT = K / 64;
    stage(0, 0);
    asm volatile("s_waitcnt vmcnt(0) lgkmcnt(0)" ::: "memory");
    __builtin_amdgcn_s_barrier();

    int cur = 0;
    for (int kt = 0; kt < KT; ++kt) {
        if (kt + 1 < KT) stage(cur ^ 1, (kt + 1) * 64);   // prefetch overlaps MFMA
        const bf16_t* lA = smem + cur * 16384;
        const bf16_t* lB = lA + 8192;
        #pragma unroll
        for (int ks8 = 0; ks8 < 8; ks8 += 4) {
            const int c8 = (ks8 + (lane >> 4)) ^ (lane & 7);   // swizzled read col8
            bf16x8 af[4], bfv[4];
            #pragma unroll
            for (int i = 0; i < 4; i++)
                af[i] = *(const bf16x8*)&lA[(wr + i * 16 + fr) * 64 + (c8 << 3)];
            #pragma unroll
            for (int j = 0; j < 4; j++)
                bfv[j] = *(const bf16x8*)&lB[(wc + j * 16 + fr) * 64 + (c8 << 3)];
            #pragma unroll
            for (int i = 0; i < 4; i++)
                #pragma unroll
                for (int j = 0; j < 4; j++)
                    // swapped operands (ALL modes): acc = C^T
                    acc[i][j] = __builtin_amdgcn_mfma_f32_16x16x32_bf16(
                        bfv[j], af[i], acc[i][j], 0, 0, 0);
        }
        asm volatile("s_waitcnt vmcnt(0) lgkmcnt(0)" ::: "memory");
        __builtin_amdgcn_s_barrier();
        cur ^= 1;
    }

    // ===== transposed-D epilogues: col(lane&15)=m (row), reg r = n-col offset =====
    if constexpr (MODE == 4) {
        #pragma unroll
        for (int j = 0; j < 4; j++) {
            int nl = wc + j * 16 + (lane >> 4) * 4;
            f32x4 bv = *(const f32x4*)&bias[nbase + nl];
            #pragma unroll
            for (int i = 0; i < 4; i++) {
                int grow = mbase + wr + i * 16 + fr;
                if (grow >= M) continue;
                float v0 = acc[i][j][0] + bv[0]; v0 = v0 > 0.f ? v0 : 0.f;
                float v1 = acc[i][j][1] + bv[1]; v1 = v1 > 0.f ? v1 : 0.f;
                float v2 = acc[i][j][2] + bv[2]; v2 = v2 > 0.f ? v2 : 0.f;
                float v3 = acc[i][j][3] + bv[3]; v3 = v3 > 0.f ? v3 : 0.f;
                f32x4 o = {v0, v1, v2, v3};
                *(f32x4*)&CoutF[(size_t)grow * 128 + nbase + nl] = o;
            }
        }
    } else {
        const bool isNewp = (MODE == 2 || MODE == 5) && (nbase == 512);
        if (isNewp) {
            // newp block: direct f32 stores (precision: newp stays f32)
            #pragma unroll
            for (int j = 0; j < 4; j++) {
                int nl = wc + j * 16 + (lane >> 4) * 4;
                f32x4 bv = *(const f32x4*)&bias[nbase + nl];
                #pragma unroll
                for (int i = 0; i < 4; i++) {
                    int grow = mbase + wr + i * 16 + fr;
                    if (grow >= M) continue;
                    float v0 = acc[i][j][0] + bv[0]; v0 = v0 > 0.f ? v0 : 0.f;
                    float v1 = acc[i][j][1] + bv[1]; v1 = v1 > 0.f ? v1 : 0.f;
                    float v2 = acc[i][j][2] + bv[2]; v2 = v2 > 0.f ? v2 : 0.f;
                    float v3 = acc[i][j][3] + bv[3]; v3 = v3 > 0.f ? v3 : 0.f;
                    f32x4 o = {v0, v1, v2, v3};
                    *(f32x4*)&CoutF[(size_t)grow * 128 + nl] = o;   // nbase+nl-512==nl
                }
            }
        } else {
            // per-m-row reciprocal counts (MODE 3 only): m-row = wr + i*16 + fr
            float rcv[4];
            if constexpr (MODE == 3) {
                #pragma unroll
                for (int i = 0; i < 4; i++) {
                    int grow = mbase + wr + i * 16 + fr;
                    if (grow > M - 1) grow = M - 1;
                    float c = countsIn[grow]; c = c > 1.f ? c : 1.f;
                    rcv[i] = 1.f / c;
                }
            }
            // restage C^T-tile into LDS (m-major), then coalesced row stores
            #pragma unroll
            for (int j = 0; j < 4; j++) {
                int nl = wc + j * 16 + (lane >> 4) * 4;
                f32x4 bv = *(const f32x4*)&bias[nbase + nl];
                #pragma unroll
                for (int i = 0; i < 4; i++) {
                    int ml = wr + i * 16 + fr;
                    float s = (MODE == 3) ? rcv[i] : 1.f;
                    float v0 = acc[i][j][0] * s + bv[0]; v0 = v0 > 0.f ? v0 : 0.f;
                    float v1 = acc[i][j][1] * s + bv[1]; v1 = v1 > 0.f ? v1 : 0.f;
                    float v2 = acc[i][j][2] * s + bv[2]; v2 = v2 > 0.f ? v2 : 0.f;
                    float v3 = acc[i][j][3] * s + bv[3]; v3 = v3 > 0.f ? v3 : 0.f;
                    bf16x4 pv;
                    pv[0] = (bf16_t)v0; pv[1] = (bf16_t)v1;
                    pv[2] = (bf16_t)v2; pv[3] = (bf16_t)v3;
                    *(bf16x4*)&smem[ml * LDN + nl] = pv;
                }
            }
            __syncthreads();
            const bool isS = (nbase < 512);      // MODE 2/5 s-vs-o half
            #pragma unroll
            for (int rr = 0; rr < 8; ++rr) {
                int row  = rr * 16 + (tid >> 4);
                int grow = mbase + row;
                if (grow >= M) continue;
                bf16x8 v = *(const bf16x8*)&smem[row * LDN + (tid & 15) * 8];
                if constexpr (MODE == 1 || MODE == 3) {
                    *(bf16x8*)&CoutB[(size_t)grow * 512 + nbase + (tid & 15) * 8] = v;
                } else if constexpr (MODE == 2) {
                    int cb = isS ? nbase : (nbase - 128);
                    *(bf16x8*)&CoutB[(size_t)grow * 1024 + cb + (tid & 15) * 8] = v;
                } else {   // MODE 5: scatter to poolSrc[slot][512]
                    int cb2  = isS ? nbase : (nbase - 640);
                    int drow = isS ? sIdxL[row] : oIdxL[row];
                    *(bf16x8*)&CoutB[(size_t)drow * 512 + cb2 + (tid & 15) * 8] = v;
                }
            }
        }
    }
}

// fused prologue: obj f32->bf16 (1.6M x8), 4 weight transposes (1,114,112), counts
__global__ void prep_k(const float* __restrict__ obj, bf16_t* __restrict__ objB,
                       const float* __restrict__ W1, bf16_t* __restrict__ W1t,
                       const float* __restrict__ W2, bf16_t* __restrict__ W2t,
                       const float* __restrict__ W3, bf16_t* __restrict__ W3t,
                       const float* __restrict__ W4, bf16_t* __restrict__ W4t,
                       const int* __restrict__ edges, float* __restrict__ counts) {
    int idx = blockIdx.x * 256 + threadIdx.x;
    if (idx < 1600000) {
        bf16x8 v = cvt8(obj + (size_t)idx * 8);
        *(bf16x8*)(objB + (size_t)idx * 8) = v;
        return;
    }
    idx -= 1600000;
    if (idx < 1114112) {
        const float* in; bf16_t* out; int K, N;
        if (idx < 196608)       { in = W1; out = W1t; K = 384; N = 512;  }
        else if (idx < 786432)  { in = W2; out = W2t; K = 512; N = 1152; idx -= 196608; }
        else if (idx < 1048576) { in = W3; out = W3t; K = 512; N = 512;  idx -= 786432; }
        else                    { in = W4; out = W4t; K = 512; N = 128;  idx -= 1048576; }
        int k = idx / N, n = idx - k * N;
        out[n * K + k] = (bf16_t)in[idx];
        return;
    }
    idx -= 1114112;
    if (idx < T_N) {
        unsafeAtomicAdd(&counts[edges[2 * idx]],     1.f);
        unsafeAtomicAdd(&counts[edges[2 * idx + 1]], 1.f);
    }
}

// per-block sums of (int)counts
__launch_bounds__(1024)
__global__ void scan1_k(const float* __restrict__ counts, int* __restrict__ bsum) {
    __shared__ int wsum[16];
    const int tid = threadIdx.x, lane = tid & 63, wv = tid >> 6;
    int i = blockIdx.x * 1024 + tid;
    int v = (i < O_N) ? (int)counts[i] : 0;
    #pragma unroll
    for (int d = 1; d < 64; d <<= 1) v += __shfl_xor(v, d, 64);
    if (lane == 0) wsum[wv] = v;
    __syncthreads();
    if (tid == 0) {
        int s = 0;
        #pragma unroll
        for (int k = 0; k < 16; ++k) s += wsum[k];
        bsum[blockIdx.x] = s;
    }
}

// fused scan2+scan3: each block computes its own bsum prefix, then local scan.
__launch_bounds__(1024)
__global__ void scan23_k(const float* __restrict__ counts, const int* __restrict__ bsum,
                         int* __restrict__ offsets, int* __restrict__ cursor) {
    __shared__ int wsum[16];
    __shared__ int pre2[2];
    const int tid = threadIdx.x, lane = tid & 63, wv = tid >> 6;
    int i = blockIdx.x * 1024 + tid;
    int x = (i < O_N) ? (int)counts[i] : 0;
    int v = x;
    #pragma unroll
    for (int d = 1; d < 64; d <<= 1) {
        int u = __shfl_up(v, d, 64);
        if (lane >= d) v += u;
    }
    if (lane == 63) wsum[wv] = v;
    if (tid < 128) {                       // prefix of bsum[0..blockIdx.x)
        int b = (tid < blockIdx.x) ? bsum[tid] : 0;   // blockIdx.x <= 97 < 128
        #pragma unroll
        for (int d = 1; d < 64; d <<= 1) b += __shfl_xor(b, d, 64);
        if (lane == 0) pre2[tid >> 6] = b;
    }
    __syncthreads();
    if (tid == 0) {
        int run = pre2[0] + pre2[1];
        #pragma unroll
        for (int k = 0; k < 16; ++k) { int t2 = wsum[k]; wsum[k] = run; run += t2; }
        if (blockIdx.x == SCB - 1) offsets[O_N] = run;
    }
    __syncthreads();
    if (i < O_N) { int e = wsum[wv] + (v - x); offsets[i] = e; cursor[i] = e; }
}

// slot assignment: slots[p]=(t<<1)|half (legacy pool) AND sslot2[2t]={p,q} (scatter)
__global__ void fill_k(const int* __restrict__ edges, int* __restrict__ cursor,
                       int* __restrict__ slots, int* __restrict__ sslot2) {
    int t = blockIdx.x * 256 + threadIdx.x;
    if (t < T_N) {
        int s = edges[2 * t], o = edges[2 * t + 1];
        int p = atomicAdd(&cursor[s], 1);
        slots[p] = t << 1;
        int q = atomicAdd(&cursor[o], 1);
        slots[q] = (t << 1) | 1;
        sslot2[2 * t]     = p;
        sslot2[2 * t + 1] = q;
    }
}

// scatter-mode pool: ONE WAVE PER OBJECT (R12-verified 117us), 4-deep pipelining.
// R10 (8192 waves, 13 obj/wave) and R13 (12500 waves, 8 obj/wave) both regressed:
// per-wave object-grouping serializes chains; 100K-wave churn IS the latency hiding.
__launch_bounds__(256)
__global__ void poolS_k(const bf16_t* __restrict__ poolSrc,
                        const int* __restrict__ offsets,
                        bf16_t* __restrict__ pooledB) {
    const int gw   = (blockIdx.x * 256 + threadIdx.x) >> 6;
    const int lane = threadIdx.x & 63;
    if (gw >= O_N) return;
    const int s0 = offsets[gw], s1 = offsets[gw + 1];
    float acc[8];
    #pragma unroll
    for (int l = 0; l < 8; l++) acc[l] = 0.f;
    int j = s0;
    for (; j + 3 < s1; j += 4) {           // 4-deep: all four loads in flight
        bf16x8 a = *(const bf16x8*)(poolSrc + (size_t)j * 512 + lane * 8);
        bf16x8 b = *(const bf16x8*)(poolSrc + (size_t)(j + 1) * 512 + lane * 8);
        bf16x8 c = *(const bf16x8*)(poolSrc + (size_t)(j + 2) * 512 + lane * 8);
        bf16x8 d = *(const bf16x8*)(poolSrc + (size_t)(j + 3) * 512 + lane * 8);
        #pragma unroll
        for (int l = 0; l < 8; l++)
            acc[l] += ((float)a[l] + (float)b[l]) + ((float)c[l] + (float)d[l]);
    }
    for (; j < s1; ++j) {
        bf16x8 a = *(const bf16x8*)(poolSrc + (size_t)j * 512 + lane * 8);
        #pragma unroll
        for (int l = 0; l < 8; l++) acc[l] += (float)a[l];
    }
    bf16x8 o;
    #pragma unroll
    for (int l = 0; l < 8; l++) o[l] = (bf16_t)acc[l];
    *(bf16x8*)(pooledB + (size_t)gw * 512 + lane * 8) = o;
}

// legacy pool (fallback): wave-cooperative slot preload + shfl broadcast.
template<bool FIRST>
__launch_bounds__(256)
__global__ void pool_k(const bf16_t* __restrict__ newT, const int* __restrict__ offsets,
                       const int* __restrict__ slots, bf16_t* __restrict__ pooledB,
                       int tbase, int tcount) {
    const int gw   = (blockIdx.x * 256 + threadIdx.x) >> 6;
    const int lane = threadIdx.x & 63;
    if (gw >= O_N) return;
    const int s0 = offsets[gw], s1 = offsets[gw + 1];
    float acc[8];
    #pragma unroll
    for (int l = 0; l < 8; l++) acc[l] = 0.f;
    for (int base = s0; base < s1; base += 64) {
        int nn = s1 - base; if (nn > 64) nn = 64;
        int myslot = (lane < nn) ? slots[base + lane] : 0;   // one coalesced load
        for (int j = 0; j < nn; ++j) {
            int sl = __shfl(myslot, j, 64);
            int lt = (sl >> 1) - tbase;
            if ((unsigned)lt >= (unsigned)tcount) continue;
            const bf16_t* p = newT + (size_t)lt * 1024 + (sl & 1) * 512 + lane * 8;
            bf16x8 v = *(const bf16x8*)p;
            #pragma unroll
            for (int l = 0; l < 8; l++) acc[l] += (float)v[l];
        }
    }
    bf16_t* dst = pooledB + (size_t)gw * 512 + lane * 8;
    if constexpr (!FIRST) {
        bf16x8 prev = *(const bf16x8*)dst;
        #pragma unroll
        for (int l = 0; l < 8; l++) acc[l] += (float)prev[l];
    }
    bf16x8 o;
    #pragma unroll
    for (int l = 0; l < 8; l++) o[l] = (bf16_t)acc[l];
    *(bf16x8*)dst = o;
}

extern "C" void kernel_launch(void* const* d_in, const int* in_sizes, int n_in,
                              void* d_out, int out_size, void* d_ws, size_t ws_size,
                              hipStream_t stream) {
    const float* obj  = (const float*)d_in[0];
    const float* pred = (const float*)d_in[1];
    const int*   edges= (const int*)d_in[2];
    const float* W1 = (const float*)d_in[3];
    const float* b1 = (const float*)d_in[4];
    const float* W2 = (const float*)d_in[5];
    const float* b2 = (const float*)d_in[6];
    const float* W3 = (const float*)d_in[7];
    const float* b3 = (const float*)d_in[8];
    const float* W4 = (const float*)d_in[9];
    const float* b4 = (const float*)d_in[10];
    float* out = (float*)d_out;   // [new_obj O_N*128 | new_p T_N*128], f32

    char* ws = (char*)d_ws;
    auto AL = [](size_t x) { return (x + 255) & ~(size_t)255; };

    // ---- small fixed region (both paths) ----
    size_t o_counts = 0;
    size_t o_offs   = AL(o_counts + (size_t)O_N * 4);
    size_t o_curs   = AL(o_offs   + (size_t)(O_N + 1) * 4);
    size_t o_bsum   = AL(o_curs   + (size_t)O_N * 4);
    size_t o_slots  = AL(o_bsum   + (size_t)128 * 4);
    size_t o_ss2    = AL(o_slots  + (size_t)2 * T_N * 4);     // slots 1.6 MB
    size_t o_objB   = AL(o_ss2    + (size_t)2 * T_N * 4);     // sslot2 1.6 MB
    size_t o_w1     = AL(o_objB   + (size_t)O_N * 128 * 2);   // objB 25.6 MB
    size_t o_w2     = AL(o_w1 + (size_t)384 * 512 * 2);
    size_t o_w3     = AL(o_w2 + (size_t)512 * 1152 * 2);
    size_t o_w4     = AL(o_w3 + (size_t)512 * 512 * 2);
    size_t o_end    = AL(o_w4 + (size_t)512 * 128 * 2);       // ~32.3 MB

    const size_t pbSz = (size_t)O_N * 512 * 2;                // pooledB 102.4 MB
    const size_t psSz = (size_t)2 * T_N * 512 * 2;            // poolSrc 409.6 MB
    const size_t t3sz = (size_t)O_N * 512 * 2;                // 102.4 MB

    // Tier A (scatter, NCH=4 — R12-verified): aliasing keeps cost ~544 MB:
    //   hbuf region sized max(R*1024, pbSz) = pbSz; reused as pooledB;
    //   poolSrc reused as t3 after poolS.
    bool scatter = false;
    const int NCH_SC = 4;
    {
        size_t hb = (size_t)(T_N / NCH_SC) * 1024; if (hb < pbSz) hb = pbSz;
        size_t need = o_end + AL(hb) + psSz;                  // t3sz <= psSz
        if (ws_size >= need) scatter = true;
    }
    int NCH = NCH_SC;
    if (!scatter) {   // fallback: pooledB must persist across chunks -> own region
        NCH = 8;
        for (int n : {2, 4}) {
            size_t R = (size_t)T_N / n;
            size_t chunk = AL(R * 1024) + R * 2048;
            size_t need  = o_end + AL(pbSz) + (chunk > t3sz ? chunk : t3sz);
            if (ws_size >= need) { NCH = n; break; }
        }
    }
    const int R  = T_N / NCH;
    const int MB = (R + 127) / 128;

    float*  counts  = (float*)(ws + o_counts);
    int*    offs    = (int*)(ws + o_offs);
    int*    curs    = (int*)(ws + o_curs);
    int*    bsum    = (int*)(ws + o_bsum);
    int*    slots   = (int*)(ws + o_slots);
    int*    sslot2  = (int*)(ws + o_ss2);
    bf16_t* objB    = (bf16_t*)(ws + o_objB);
    bf16_t* W1t     = (bf16_t*)(ws + o_w1);
    bf16_t* W2t     = (bf16_t*)(ws + o_w2);
    bf16_t* W3t     = (bf16_t*)(ws + o_w3);
    bf16_t* W4t     = (bf16_t*)(ws + o_w4);

    bf16_t *hbuf, *pooledB, *stage2, *t3;
    if (scatter) {
        size_t hb = (size_t)R * 1024; if (hb < pbSz) hb = pbSz;
        hbuf    = (bf16_t*)(ws + o_end);
        pooledB = hbuf;                          // aliases hbuf (dead before poolS)
        stage2  = (bf16_t*)(ws + o_end + AL(hb));   // poolSrc
        t3      = stage2;                        // aliases poolSrc (dead after poolS)
    } else {
        pooledB = (bf16_t*)(ws + o_end);
        hbuf    = (bf16_t*)(ws + o_end + AL(pbSz));
        stage2  = (bf16_t*)((char*)hbuf + AL((size_t)R * 1024));  // newT
        t3      = hbuf;                          // reuse after pooling done
    }

    hipMemsetAsync(counts, 0, (size_t)O_N * 4, stream);

    prep_k<<<(2914112 + 255) / 256, 256, 0, stream>>>(
        obj, objB, W1, W1t, W2, W2t, W3, W3t, W4, W4t, edges, counts);
    scan1_k<<<SCB, 1024, 0, stream>>>(counts, bsum);
    scan23_k<<<SCB, 1024, 0, stream>>>(counts, bsum, offs, curs);
    fill_k<<<(T_N + 255) / 256, 256, 0, stream>>>(edges, curs, slots, sslot2);

    for (int c = 0; c < NCH; ++c) {
        const int row0 = c * R;
        gemm_k<1, 512, 384><<<dim3(4, MB), 256, 0, stream>>>(
            nullptr, objB, pred + (size_t)row0 * 128, edges + 2 * row0,
            nullptr, W1t, b1, hbuf, nullptr, R);
        if (scatter) {
            gemm_k<5, 1152, 512><<<dim3(9, MB), 256, 0, stream>>>(
                hbuf, nullptr, nullptr, sslot2 + 2 * row0,
                nullptr, W2t, b2, stage2,
                out + (size_t)O_N * 128 + (size_t)row0 * 128, R);
        } else {
            gemm_k<2, 1152, 512><<<dim3(9, MB), 256, 0, stream>>>(
                hbuf, nullptr, nullptr, nullptr,
                nullptr, W2t, b2, stage2,
                out + (size_t)O_N * 128 + (size_t)row0 * 128, R);
            if (c == 0)
                pool_k<true><<<(O_N * 64 + 255) / 256, 256, 0, stream>>>(
                    stage2, offs, slots, pooledB, row0, R);
            else
                pool_k<false><<<(O_N * 64 + 255) / 256, 256, 0, stream>>>(
                    stage2, offs, slots, pooledB, row0, R);
        }
    }
    if (scatter)
        poolS_k<<<(O_N * 64 + 255) / 256, 256, 0, stream>>>(stage2, offs, pooledB);

    // t3 = relu((pooledB @ W3) * 1/max(counts,1) + b3)   (div fused into restage)
    gemm_k<3, 512, 512><<<dim3(4, 782), 256, 0, stream>>>(
        pooledB, nullptr, nullptr, nullptr, counts,
        W3t, b3, t3, nullptr, O_N);
    // new_obj = relu(t3 @ W4 + b4)
    gemm_k<4, 128, 512><<<dim3(1, 782), 256, 0, stream>>>(
        t3, nullptr, nullptr, nullptr, nullptr,
        W4t, b4, nullptr, out, O_N);
}